// Round 7
// baseline (6211.054 us; speedup 1.0000x reference)
//
#include <hip/hip_runtime.h>
#include <hip/hip_bf16.h>

// ProductGraphsModel: 2x256 independent 5-layer GCN stacks + mean-pool + FC.
// Round 7: aggregation as dense MFMA GEMM.
//  - prep: degrees in LDS, scatter normalized adjacency into fp32 AD (atomic),
//    then split to bf16 hi/lo ADpack. Self-loops folded in.
//  - transform GEMM: hT[c][node] = Wt @ x   (A=WTpack, B=xpack, both natural)
//  - agg GEMM:       x'[t][c]   = AD @ hT   (A=ADpack, B=hTpack, both natural)
//    -> zero transposes anywhere; state alternates operand sides.
//  - both GEMMs: 3-term bf16 hi/lo split via compile-time offset tables,
//    BM=BN=128, BK=32, 256 thr, double-buffered 32KB LDS, XCD swizzle.

#define G_   256
#define N_   512
#define E_   16384
#define H_   256
#define KP_  512         // xpack row pitch (shorts): [hi 256 | lo 256]
#define FIN  4
#define FG   6
#define C_   3
#define L_   5
#define B_   512         // 2*G_ instances (home then away)

typedef __attribute__((ext_vector_type(4))) float f32x4;
typedef __attribute__((ext_vector_type(8))) short bf16x8;

__device__ __forceinline__ void gload_lds16(const void* g, void* l) {
    __builtin_amdgcn_global_load_lds(
        (const __attribute__((address_space(1))) void*)g,
        (__attribute__((address_space(3))) void*)l, 16, 0, 0);
}

// m204 bijective chunked swizzle: orig%8 = HW XCD.
__device__ __forceinline__ int xcd_chunk_swizzle(int orig, int nwg) {
    const int q = nwg >> 3, r = nwg & 7, x = orig & 7;
    const int base = (x < r) ? x * (q + 1) : r * (q + 1) + (x - r) * q;
    return base + (orig >> 3);
}

// ---------------------------------------------------------------- prep ----
// Degrees (self-loop weight 1) in LDS, dinv, then scatter normalized
// adjacency AD[t][s] += dinv[s]*ew*dinv[t] (fp32 global atomics; AD was
// memset to 0). Self-loop AD[n][n] += dinv[n]^2.
__global__ __launch_bounds__(256) void prep_kernel(
    const int* __restrict__ hei, const int* __restrict__ aei,
    const float* __restrict__ hew, const float* __restrict__ aew,
    int inst0, float* __restrict__ ADf)
{
    const int ci = blockIdx.x;
    const int b  = inst0 + ci;
    const int g  = (b < G_) ? b : b - G_;
    const int*   ei = ((b < G_) ? hei : aei) + (size_t)g * 2 * E_;
    const float* ew = ((b < G_) ? hew : aew) + (size_t)g * E_;
    const int* srcA = ei;
    const int* dstA = ei + E_;

    __shared__ float degS[N_];
    const int tid = threadIdx.x;
    for (int n = tid; n < N_; n += 256) degS[n] = 1.0f;
    __syncthreads();
    for (int e = tid; e < E_; e += 256) atomicAdd(&degS[dstA[e]], ew[e]);
    __syncthreads();
    for (int n = tid; n < N_; n += 256) degS[n] = rsqrtf(degS[n]);
    __syncthreads();

    float* AD = ADf + (size_t)ci * N_ * N_;
    for (int n = tid; n < N_; n += 256)
        atomicAdd(&AD[(size_t)n * (N_ + 1)], degS[n] * degS[n]);   // [n][n]
    for (int e = tid; e < E_; e += 256) {
        const int s = srcA[e], t = dstA[e];
        atomicAdd(&AD[(size_t)t * N_ + s], degS[s] * ew[e] * degS[t]);
    }
}

// ------------------------------------------------------------- AD split ----
// ADf[ci*512+t][512] fp32 -> ADpack[ci*512+t][1024] bf16 [hi 512 | lo 512].
__global__ __launch_bounds__(256) void adsplit_kernel(
    const float* __restrict__ ADf, __hip_bfloat16* __restrict__ ADp)
{
    const size_t row = blockIdx.x;
    const int    s   = threadIdx.x * 2;
    const float2 v = *(const float2*)(ADf + row * N_ + s);
    const __hip_bfloat16 h0 = __float2bfloat16(v.x);
    const __hip_bfloat16 h1 = __float2bfloat16(v.y);
    __hip_bfloat16* o = ADp + row * 1024;
    o[s]       = h0;
    o[s + 1]   = h1;
    o[512 + s]     = __float2bfloat16(v.x - __bfloat162float(h0));
    o[512 + s + 1] = __float2bfloat16(v.y - __bfloat162float(h1));
}

// ------------------------------------------------ W transpose + pack ----
// Wh[l][k][n] fp32 -> WTpack[l][n][512] bf16: [k]=hi, [256+k]=lo.
__global__ __launch_bounds__(256) void wsplit_kernel(
    const float* __restrict__ Wh, __hip_bfloat16* __restrict__ WTpack)
{
    const int idx = blockIdx.x * 256 + threadIdx.x;
    if (idx >= (L_ - 1) * H_ * H_) return;
    const int l = idx >> 16, rem = idx & 65535;
    const int n = rem >> 8, k = rem & 255;
    const float w = Wh[(size_t)l * H_ * H_ + (size_t)k * H_ + n];
    const __hip_bfloat16 hi = __float2bfloat16(w);
    const __hip_bfloat16 lo = __float2bfloat16(w - __bfloat162float(hi));
    __hip_bfloat16* base = WTpack + ((size_t)(l * H_ + n)) * KP_;
    base[k] = hi; base[H_ + k] = lo;
}

// ---------------------------------------------- layer-0 transform (hT) ----
// hT[c][node] = x @ W0 written transposed+split: 32 blocks/inst
// (2 node-halves x 16 c-groups); lane = node -> coalesced stores.
__global__ __launch_bounds__(256) void xw0T_kernel(
    const float* __restrict__ hx, const float* __restrict__ ax,
    const float* __restrict__ W0, int inst0, __hip_bfloat16* __restrict__ hT)
{
    const int ci = blockIdx.x >> 5;
    const int rr = blockIdx.x & 31;
    const int n  = ((rr >> 4) << 8) + threadIdx.x;
    const int c0 = (rr & 15) << 4;
    const int b  = inst0 + ci;
    const int g  = (b < G_) ? b : b - G_;
    const float4 xv = *(const float4*)(((b < G_) ? hx : ax) + ((size_t)g * N_ + n) * FIN);
    __hip_bfloat16* out = hT + (size_t)ci * 262144;
#pragma unroll
    for (int cc = 0; cc < 16; ++cc) {
        const int c = c0 + cc;
        float v = xv.x * W0[c];
        v = fmaf(xv.y, W0[H_ + c], v);
        v = fmaf(xv.z, W0[2 * H_ + c], v);
        v = fmaf(xv.w, W0[3 * H_ + c], v);
        const __hip_bfloat16 hi = __float2bfloat16(v);
        out[(size_t)c * 1024 + n]       = hi;
        out[(size_t)c * 1024 + 512 + n] = __float2bfloat16(v - __bfloat162float(hi));
    }
}

// -------------------------------------------------- split MFMA GEMM ----
// D[m][n] = sum_k A[m][k]*B[n][k] over a 3-term hi/lo offset table.
// BM=BN=128, BK=32, 256 thr (2x2 waves of 64x64), dbuf 32KB LDS.
// Output bf16 hi/lo pair at [row][col] / [row][LOOFF+col], opt bias+relu.
template<int MBLK, int NBLK, int NSTEPS, int SPT, int KPA, int KPB,
         int AO0, int AO1, int AO2, int BO0, int BO1, int BO2,
         int OPITCH, int LOOFF, bool BRELU>
__global__ __launch_bounds__(256, 3) void gemm2_kernel(
    const short* __restrict__ A, const short* __restrict__ B,
    __hip_bfloat16* __restrict__ Out, const float* __restrict__ bias,
    long aStride, long bStride, long oStride)
{
    __shared__ short lA[2][4096];
    __shared__ short lB[2][4096];
    const int tid  = threadIdx.x;
    const int w    = xcd_chunk_swizzle(blockIdx.x, gridDim.x);
    const int bpi  = MBLK * NBLK;
    const int ci   = w / bpi;
    const int r    = w % bpi;
    const int m0   = (r / NBLK) * 128;
    const int n0   = (r % NBLK) * 128;
    const short* Ab = A + (size_t)ci * aStride;
    const short* Bb = B + (size_t)ci * bStride;
    const int lane = tid & 63;
    const int wave = tid >> 6;
    const int wm   = (wave >> 1) * 64;
    const int wn   = (wave & 1) * 64;
    const int l15  = lane & 15;
    const int kb4  = lane >> 4;

    f32x4 acc[4][4];
#pragma unroll
    for (int i = 0; i < 4; ++i)
#pragma unroll
        for (int j = 0; j < 4; ++j) acc[i][j] = (f32x4)0.f;

    auto stg = [&](int buf, int ak, int bk) {
#pragma unroll
        for (int call = 0; call < 2; ++call) {
            const int c = call * 256 + tid;
            const int row = c & 127, kb = c >> 7;
            gload_lds16(Ab + (size_t)(m0 + row) * KPA + ak + (kb << 3),
                        &lA[buf][(c & ~63) << 3]);
            gload_lds16(Bb + (size_t)(n0 + row) * KPB + bk + (kb << 3),
                        &lB[buf][(c & ~63) << 3]);
        }
    };
    auto comp = [&](int buf) {
        bf16x8 av[4];
#pragma unroll
        for (int mf = 0; mf < 4; ++mf)
            av[mf] = *(const bf16x8*)&lA[buf][(kb4 * 128 + wm + mf * 16 + l15) << 3];
#pragma unroll
        for (int nf = 0; nf < 4; ++nf) {
            const bf16x8 bv = *(const bf16x8*)&lB[buf][(kb4 * 128 + wn + nf * 16 + l15) << 3];
#pragma unroll
            for (int mf = 0; mf < 4; ++mf)
                acc[mf][nf] = __builtin_amdgcn_mfma_f32_16x16x32_bf16(av[mf], bv, acc[mf][nf], 0, 0, 0);
        }
    };

    stg(0, AO0, BO0);
    __syncthreads();
#pragma unroll 4
    for (int st = 0; st < NSTEPS - 1; ++st) {
        const int s1 = st + 1;
        const int t1 = s1 / SPT, k1 = (s1 % SPT) * 32;
        stg(s1 & 1, (t1 == 0 ? AO0 : t1 == 1 ? AO1 : AO2) + k1,
                    (t1 == 0 ? BO0 : t1 == 1 ? BO1 : BO2) + k1);
        comp(st & 1);
        __syncthreads();
    }
    comp((NSTEPS - 1) & 1);

#pragma unroll
    for (int mf = 0; mf < 4; ++mf) {
        const int r0 = m0 + wm + mf * 16 + (kb4 << 2);
#pragma unroll
        for (int nf = 0; nf < 4; ++nf) {
            const int col = n0 + wn + nf * 16 + l15;
            const float bv = BRELU ? bias[col] : 0.f;
            const f32x4 v = acc[mf][nf];
#pragma unroll
            for (int j = 0; j < 4; ++j) {
                float o = v[j] + bv;
                if (BRELU) o = fmaxf(o, 0.f);
                const __hip_bfloat16 hi = __float2bfloat16(o);
                const __hip_bfloat16 lo = __float2bfloat16(o - __bfloat162float(hi));
                __hip_bfloat16* op = Out + (size_t)ci * oStride + (size_t)(r0 + j) * OPITCH;
                op[col] = hi;
                op[LOOFF + col] = lo;
            }
        }
    }
}

// ----------------------------------------------------------------- pool ----
__global__ __launch_bounds__(256) void pool_kernel(
    const __hip_bfloat16* __restrict__ xpack, int inst0, float* __restrict__ pooled)
{
    const int ci = blockIdx.x;
    const int c  = threadIdx.x;
    const __hip_bfloat16* xp = xpack + (size_t)ci * N_ * KP_;
    float a0 = 0.f, a1 = 0.f, a2 = 0.f, a3 = 0.f;
    for (int n = 0; n < N_; n += 4) {
        a0 += __bfloat162float(xp[(size_t)(n + 0) * KP_ + c]) + __bfloat162float(xp[(size_t)(n + 0) * KP_ + H_ + c]);
        a1 += __bfloat162float(xp[(size_t)(n + 1) * KP_ + c]) + __bfloat162float(xp[(size_t)(n + 1) * KP_ + H_ + c]);
        a2 += __bfloat162float(xp[(size_t)(n + 2) * KP_ + c]) + __bfloat162float(xp[(size_t)(n + 2) * KP_ + H_ + c]);
        a3 += __bfloat162float(xp[(size_t)(n + 3) * KP_ + c]) + __bfloat162float(xp[(size_t)(n + 3) * KP_ + H_ + c]);
    }
    pooled[(size_t)(inst0 + ci) * H_ + c] = (a0 + a1 + a2 + a3) * (1.0f / N_);
}

// ------------------------------------------------------------------- fc ----
__global__ __launch_bounds__(256) void fc_kernel(
    const float* __restrict__ pooled, const float* __restrict__ hf,
    const float* __restrict__ af, const float* __restrict__ fcW,
    const float* __restrict__ fcb, float* __restrict__ outp)
{
    const int idx = blockIdx.x * 256 + threadIdx.x;
    if (idx >= G_ * C_) return;
    const int gi = idx / C_;
    const int c  = idx % C_;
    float acc = fcb[c];
    const float* ph = pooled + (size_t)gi * H_;
    const float* pa = pooled + (size_t)(G_ + gi) * H_;
    for (int j = 0; j < H_; ++j) acc += ph[j] * fcW[j * C_ + c];
    for (int j = 0; j < FG; ++j) acc += hf[gi * FG + j] * fcW[(H_ + j) * C_ + c];
    for (int j = 0; j < H_; ++j) acc += pa[j] * fcW[(H_ + FG + j) * C_ + c];
    for (int j = 0; j < FG; ++j) acc += af[gi * FG + j] * fcW[(H_ + FG + H_ + j) * C_ + c];
    outp[idx] = acc;
}

// ----------------------------------------------------------------- host ----
static inline size_t align_up(size_t v, size_t a) { return (v + a - 1) & ~(a - 1); }

extern "C" void kernel_launch(void* const* d_in, const int* in_sizes, int n_in,
                              void* d_out, int out_size, void* d_ws, size_t ws_size,
                              hipStream_t stream)
{
    const float* hx  = (const float*)d_in[0];
    const float* ax  = (const float*)d_in[1];
    const int*   hei = (const int*)d_in[2];
    const int*   aei = (const int*)d_in[3];
    const float* hew = (const float*)d_in[4];
    const float* aew = (const float*)d_in[5];
    const float* hf  = (const float*)d_in[6];
    const float* af  = (const float*)d_in[7];
    const float* W0  = (const float*)d_in[8];
    const float* Wh  = (const float*)d_in[9];
    const float* bs  = (const float*)d_in[10];
    const float* fcW = (const float*)d_in[11];
    const float* fcb = (const float*)d_in[12];
    float* outp = (float*)d_out;

    const size_t pooled_b = align_up((size_t)B_ * H_ * sizeof(float), 256);
    const size_t wtp_b    = align_up((size_t)(L_ - 1) * H_ * KP_ * sizeof(__hip_bfloat16), 256);
    const size_t adf_b = (size_t)N_ * N_ * sizeof(float);            // 1 MiB
    const size_t adp_b = (size_t)N_ * 1024 * sizeof(__hip_bfloat16); // 1 MiB
    const size_t ht_b  = (size_t)H_ * 1024 * sizeof(__hip_bfloat16); // 512 KiB
    const size_t xp_b  = (size_t)N_ * KP_ * sizeof(__hip_bfloat16);  // 512 KiB
    const size_t per_inst = adf_b + adp_b + ht_b + xp_b;
    const size_t fixed = pooled_b + wtp_b;

    int CB = (int)((ws_size > fixed) ? (ws_size - fixed) / per_inst : 0);
    if (CB < 1) CB = 1;
    if (CB > B_) CB = B_;

    char* p = (char*)d_ws;
    float* pooled = (float*)p;                   p += pooled_b;
    __hip_bfloat16* WTpack = (__hip_bfloat16*)p; p += wtp_b;
    float* ADf32 = (float*)p;                    p += (size_t)CB * adf_b;
    __hip_bfloat16* ADpack = (__hip_bfloat16*)p; p += (size_t)CB * adp_b;
    __hip_bfloat16* hTpack = (__hip_bfloat16*)p; p += (size_t)CB * ht_b;
    __hip_bfloat16* xpack  = (__hip_bfloat16*)p;

    wsplit_kernel<<<((L_ - 1) * H_ * H_ + 255) / 256, 256, 0, stream>>>(Wh, WTpack);

    for (int i0 = 0; i0 < B_; i0 += CB) {
        const int cb = (B_ - i0 < CB) ? (B_ - i0) : CB;

        hipMemsetAsync(ADf32, 0, (size_t)cb * adf_b, stream);
        prep_kernel<<<cb, 256, 0, stream>>>(hei, aei, hew, aew, i0, ADf32);
        adsplit_kernel<<<cb * N_, 256, 0, stream>>>(ADf32, ADpack);
        xw0T_kernel<<<cb * 32, 256, 0, stream>>>(hx, ax, W0, i0, hTpack);

        for (int l = 0; l < L_; ++l) {
            if (l > 0) {
                // hT[c][node] = Wt @ x : M=256(c), N=512(node), terms
                // (Whi,xhi),(Wlo,xhi),(Whi,xlo) over K=256 each.
                gemm2_kernel<2, 4, 24, 8, 512, 512, 0, 256, 0, 0, 0, 256,
                             1024, 512, false><<<cb * 8, 256, 0, stream>>>(
                    (const short*)(WTpack + (size_t)(l - 1) * H_ * KP_),
                    (const short*)xpack, hTpack, nullptr,
                    0L, 262144L, 262144L);
            }
            // x'[t][c] = AD @ hT : M=512(t), N=256(c), terms
            // (ADhi,hhi),(ADlo,hhi),(ADhi,hlo) over K=512 each. bias+relu.
            gemm2_kernel<4, 2, 48, 16, 1024, 1024, 0, 512, 0, 0, 0, 512,
                         512, 256, true><<<cb * 8, 256, 0, stream>>>(
                (const short*)ADpack, (const short*)hTpack, xpack,
                bs + (size_t)l * H_,
                524288L, 262144L, 262144L);
        }
        pool_kernel<<<cb, 256, 0, stream>>>(xpack, i0, pooled);
    }

    fc_kernel<<<(G_ * C_ + 255) / 256, 256, 0, stream>>>(pooled, hf, af, fcW, fcb, outp);
}

// Round 9
// 3452.842 us; speedup vs baseline: 1.7988x; 1.7988x over previous
//
#include <hip/hip_runtime.h>
#include <hip/hip_bf16.h>
#include <hip/hip_fp16.h>

// ProductGraphsModel: 2x256 independent 5-layer GCN stacks + mean-pool + FC.
// Round 9 (= round-8 sparse design + numerics hardening):
//  - edges packed (trunc23(w)) | src(9b): 1 readlane/edge, SALU unpack,
//    weight rel err 2^-15 (vs bf16 2^-9).
//  - agg gathers h as fp16 (128 ch/block in 128 KiB LDS): 1 ds_read_b32 =
//    2 channels; rel err 2^-11. Row-half split halves edge visits.
//  - ping-pong: xpA = h (fp16, pitch 256) / xpB = x (bf16 hi|lo, pitch 512).
//  - GEMM: round-6 K=512 [hi|lo] offset-table split (validated 1.9e-6),
//    epilogue writes fp16 h.

#define G_   256
#define N_   512
#define E_   16384
#define ET_  (E_ + N_)   // edges + self-loops
#define H_   256
#define KP_  512         // xpB row pitch (shorts): [hi 256 | lo 256]
#define KPH  256         // xpA row pitch (shorts): fp16 h
#define FIN  4
#define FG   6
#define C_   3
#define L_   5
#define B_   512         // 2*G_ instances (home then away)

typedef __attribute__((ext_vector_type(4))) float f32x4;
typedef __attribute__((ext_vector_type(8))) short bf16x8;

__device__ __forceinline__ void gload_lds16(const void* g, void* l) {
    __builtin_amdgcn_global_load_lds(
        (const __attribute__((address_space(1))) void*)g,
        (__attribute__((address_space(3))) void*)l, 16, 0, 0);
}

// m204 bijective chunked swizzle: orig%8 = HW XCD.
__device__ __forceinline__ int xcd_chunk_swizzle(int orig, int nwg) {
    const int q = nwg >> 3, r = nwg & 7, x = orig & 7;
    const int base = (x < r) ? x * (q + 1) : r * (q + 1) + (x - r) * q;
    return base + (orig >> 3);
}

__device__ __forceinline__ unsigned short f2bf(float f) {
    __hip_bfloat16 b = __float2bfloat16(f);
    return *reinterpret_cast<unsigned short*>(&b);
}
__device__ __forceinline__ unsigned short f2h(float f) {
    __half h = __float2half(f);
    return *reinterpret_cast<unsigned short*>(&h);
}
// w > 0, src < 512: round mantissa to 14 bits (carry into exp is OK),
// stuff src into the low 9 bits. Restore: asfloat(p & ~0x1FF).
__device__ __forceinline__ unsigned packw(float w, unsigned src) {
    unsigned b = __float_as_uint(w);
    b = (b + 0x100u) & 0xFFFFFE00u;
    return b | src;
}

// ---------------------------------------------------------------- prep ----
// CSR by dst; entry = packw(norm, src). Self-loop at slot rowptr[t].
__global__ __launch_bounds__(256) void prep_kernel(
    const int* __restrict__ hei, const int* __restrict__ aei,
    const float* __restrict__ hew, const float* __restrict__ aew,
    int inst0, unsigned* __restrict__ epack, int* __restrict__ rowptr)
{
    const int ci = blockIdx.x;
    const int b  = inst0 + ci;
    const int g  = (b < G_) ? b : b - G_;
    const int*   ei = ((b < G_) ? hei : aei) + (size_t)g * 2 * E_;
    const float* ew = ((b < G_) ? hew : aew) + (size_t)g * E_;
    const int* srcA = ei;
    const int* dstA = ei + E_;

    __shared__ float degS[N_];
    __shared__ int   cntS[N_];
    __shared__ int   startS[N_ + 1];
    __shared__ int   curS[N_];
    const int tid = threadIdx.x;

    for (int n = tid; n < N_; n += 256) { degS[n] = 1.0f; cntS[n] = 0; }  // self weight 1
    __syncthreads();
    for (int e = tid; e < E_; e += 256) {
        atomicAdd(&degS[dstA[e]], ew[e]);
        atomicAdd(&cntS[dstA[e]], 1);
    }
    __syncthreads();
    for (int n = tid; n < N_; n += 256) degS[n] = rsqrtf(degS[n]);   // dinv
    __syncthreads();
    if (tid == 0) {
        int acc = 0;
        for (int n = 0; n < N_; ++n) { startS[n] = acc; acc += cntS[n] + 1; }
        startS[N_] = acc;    // = ET_
    }
    __syncthreads();
    for (int n = tid; n <= N_; n += 256) rowptr[(size_t)ci * (N_ + 1) + n] = startS[n];
    for (int n = tid; n < N_; n += 256) {
        curS[n] = 1;                                   // slot 0 = self loop
        epack[(size_t)ci * ET_ + startS[n]] = packw(degS[n] * degS[n], (unsigned)n);
    }
    __syncthreads();
    for (int e = tid; e < E_; e += 256) {
        int t = dstA[e], s = srcA[e];
        int pos = startS[t] + atomicAdd(&curS[t], 1);
        epack[(size_t)ci * ET_ + pos] = packw(degS[s] * ew[e] * degS[t], (unsigned)s);
    }
}

// ------------------------------------------------ W transpose + pack ----
// Wh[l][k][n] fp32 -> WTpack[l][n][512] bf16: [k]=hi, [256+k]=lo.
__global__ __launch_bounds__(256) void wsplit_kernel(
    const float* __restrict__ Wh, __hip_bfloat16* __restrict__ WTpack)
{
    const int idx = blockIdx.x * 256 + threadIdx.x;
    if (idx >= (L_ - 1) * H_ * H_) return;
    const int l = idx >> 16, rem = idx & 65535;
    const int n = rem >> 8, k = rem & 255;
    const float w = Wh[(size_t)l * H_ * H_ + (size_t)k * H_ + n];
    const __hip_bfloat16 hi = __float2bfloat16(w);
    const __hip_bfloat16 lo = __float2bfloat16(w - __bfloat162float(hi));
    __hip_bfloat16* base = WTpack + ((size_t)(l * H_ + n)) * KP_;
    base[k] = hi; base[H_ + k] = lo;
}

// ---------------------------------------------------- layer-0 transform ----
// h0 = x @ W0, written fp16 into xpA (pitch 256 shorts).
__global__ __launch_bounds__(256) void xw0_kernel(
    const float* __restrict__ hx, const float* __restrict__ ax,
    const float* __restrict__ W0, int inst0, unsigned short* __restrict__ xA)
{
    const int ci = blockIdx.x >> 5;
    const int n0 = (blockIdx.x & 31) << 4;
    const int c  = threadIdx.x;
    const int b  = inst0 + ci;
    const int g  = (b < G_) ? b : b - G_;
    const float w0 = W0[c], w1 = W0[H_ + c], w2 = W0[2 * H_ + c], w3 = W0[3 * H_ + c];
    const float* x = ((b < G_) ? hx : ax) + ((size_t)g * N_ + n0) * FIN;
    unsigned short* o = xA + ((size_t)(ci * N_ + n0)) * KPH + c;
#pragma unroll
    for (int i = 0; i < 16; ++i) {
        const float4 xv = *(const float4*)&x[i * 4];
        float acc = xv.x * w0;
        acc = fmaf(xv.y, w1, acc);
        acc = fmaf(xv.z, w2, acc);
        acc = fmaf(xv.w, w3, acc);
        o[(size_t)i * KPH] = f2h(acc);
    }
}

// ----------------------------------------------------- packed MFMA GEMM ----
// h[M,256] = split-GEMM over 24 virtual BK=32 steps:
//   steps 0-7 : A hi x W hi ; 8-15 : A lo x W hi ; 16-23 : A hi x W lo.
// BM=BN=128, 256 thr (2x2 waves), double-buffered 16KB LDS.
// Output: fp16 h into xpA (pitch 256 shorts).
__global__ __launch_bounds__(256, 3) void gemm_mfma_kernel(
    const short* __restrict__ A,           // [M][512] bf16 bits [hi|lo]
    const short* __restrict__ B,           // [256][512] bf16 bits [Whi|Wlo]
    unsigned short* __restrict__ Out)      // [M][256] fp16
{
    __shared__ short lA[2][4096];
    __shared__ short lB[2][4096];

    const int tid  = threadIdx.x;
    const int w    = xcd_chunk_swizzle(blockIdx.x, gridDim.x);
    const int m0   = (w >> 1) * 128;
    const int n0   = (w & 1) * 128;
    const int lane = tid & 63;
    const int wave = tid >> 6;
    const int wm   = (wave >> 1) * 64;
    const int wn   = (wave & 1) * 64;
    const int l15  = lane & 15;
    const int kb4  = lane >> 4;

    f32x4 acc[4][4];
#pragma unroll
    for (int i = 0; i < 4; ++i)
#pragma unroll
        for (int j = 0; j < 4; ++j) acc[i][j] = (f32x4)0.f;

#define AKOF(st) ((st) < 8 ? (st) * 32 : (st) < 16 ? ((st) - 8) * 32 + 256 : ((st) - 16) * 32)
#define BKOF(st) ((st) < 8 ? (st) * 32 : (st) < 16 ? ((st) - 8) * 32 : ((st) - 16) * 32 + 256)

#define STG(buf, ak, bk) do { \
    _Pragma("unroll") for (int call = 0; call < 2; ++call) { \
        const int c = call * 256 + tid; \
        const int row = c & 127, kb = c >> 7; \
        gload_lds16(A + (size_t)(m0 + row) * KP_ + (ak) + (kb << 3), \
                    &lA[buf][(c & ~63) << 3]); \
        gload_lds16(B + (size_t)(n0 + row) * KP_ + (bk) + (kb << 3), \
                    &lB[buf][(c & ~63) << 3]); \
    } } while (0)

#define COMP(buf) do { \
    bf16x8 av[4]; \
    _Pragma("unroll") for (int mf = 0; mf < 4; ++mf) \
        av[mf] = *(const bf16x8*)&lA[buf][(kb4 * 128 + wm + mf * 16 + l15) << 3]; \
    _Pragma("unroll") for (int nf = 0; nf < 4; ++nf) { \
        const bf16x8 bv = *(const bf16x8*)&lB[buf][(kb4 * 128 + wn + nf * 16 + l15) << 3]; \
        _Pragma("unroll") for (int mf = 0; mf < 4; ++mf) \
            acc[mf][nf] = __builtin_amdgcn_mfma_f32_16x16x32_bf16(av[mf], bv, acc[mf][nf], 0, 0, 0); \
    } } while (0)

    STG(0, 0, 0);
    __syncthreads();
#pragma unroll 4
    for (int st = 0; st < 23; ++st) {
        STG((st + 1) & 1, AKOF(st + 1), BKOF(st + 1));  // async next K-step
        COMP(st & 1);                                   // compute current
        __syncthreads();                                // vmcnt+lgkm drained
    }
    COMP(1);

#pragma unroll
    for (int mf = 0; mf < 4; ++mf) {
        const int r0 = m0 + wm + mf * 16 + (kb4 << 2);
#pragma unroll
        for (int nf = 0; nf < 4; ++nf) {
            const int col = n0 + wn + nf * 16 + l15;
            const f32x4 v = acc[mf][nf];
#pragma unroll
            for (int j = 0; j < 4; ++j)
                Out[(size_t)(r0 + j) * KPH + col] = f2h(v[j]);
        }
    }
#undef STG
#undef COMP
#undef AKOF
#undef BKOF
}

// ---------------------------------------------------------- aggregation ----
// block = (instance, ch-half hc, row-half rh), 1024 thr = 16 waves x 16 rows.
// Stage fp16 h for 128 channels of ALL 512 nodes in 128 KiB LDS. Per edge:
// 1 readlane of packw, SALU unpack (w = bits&~0x1FF, src = bits&0x1FF),
// 1 ds_read_b32 (= 2 fp16 ch), 2 cvt, 2 fmac. Output: bf16 hi|lo +bias+relu.
__global__ __launch_bounds__(1024, 4) void agg_kernel(
    const unsigned short* __restrict__ xin, const unsigned* __restrict__ epack,
    const int* __restrict__ rowptr, const float* __restrict__ bias,
    unsigned short* __restrict__ xout)
{
    __shared__ unsigned hs[N_ * 64];   // 128 KiB: [node][64 dwords] = 128 fp16 ch
    const int w    = xcd_chunk_swizzle(blockIdx.x, gridDim.x);
    const int ci   = w >> 2;
    const int hc   = (w >> 1) & 1;
    const int rh   = w & 1;
    const int c0   = hc << 7;          // 0 or 128
    const int tid  = threadIdx.x;
    const int lane = tid & 63;
    const int wv   = tid >> 6;

    const unsigned short* xb = xin + (size_t)ci * (N_ * KPH) + c0;
#pragma unroll
    for (int it = 0; it < 8; ++it) {             // 8192 16B chunks / 1024 thr
        const int i = it * 1024 + tid;
        const int n = i >> 4;
        const int q = i & 15;
        gload_lds16(xb + (size_t)n * KPH + q * 8, &hs[(i & ~63) << 2]);
    }
    __syncthreads();

    const int*      rp = rowptr + (size_t)ci * (N_ + 1);
    const unsigned* ep = epack + (size_t)ci * ET_;
    const float2 bv2 = *(const float2*)(bias + c0 + 2 * lane);

#define EDGE(J, A0, A1) { \
    const unsigned p = (unsigned)__builtin_amdgcn_readlane((int)mp, i + (J)); \
    const unsigned scol = p & 0x1FFu; \
    const float wv_ = __uint_as_float(p & 0xFFFFFE00u); \
    const unsigned dv = hs[scol * 64 + lane]; \
    const float2 ff = __half22float2(*reinterpret_cast<const __half2*>(&dv)); \
    A0 = fmaf(wv_, ff.x, A0); \
    A1 = fmaf(wv_, ff.y, A1); }

    const int tbase = (rh << 8) + (wv << 4);
    for (int t = tbase; t < tbase + 16; ++t) {
        const int r0 = rp[t], r1 = rp[t + 1];
        float a00 = 0.f, a01 = 0.f, a10 = 0.f, a11 = 0.f;
        float a20 = 0.f, a21 = 0.f, a30 = 0.f, a31 = 0.f;
        for (int e0 = r0; e0 < r1; e0 += 64) {
            const int rem = r1 - e0;
            const int cnt = rem < 64 ? rem : 64;
            unsigned mp = 0;
            if (lane < rem) mp = ep[e0 + lane];
            int i = 0;
            for (; i + 8 <= cnt; i += 8) {
                EDGE(0, a00, a01) EDGE(1, a10, a11)
                EDGE(2, a20, a21) EDGE(3, a30, a31)
                EDGE(4, a00, a01) EDGE(5, a10, a11)
                EDGE(6, a20, a21) EDGE(7, a30, a31)
            }
            for (; i < cnt; ++i) { EDGE(0, a00, a01) }
        }
        const float o0 = fmaxf(a00 + a10 + a20 + a30 + bv2.x, 0.f);
        const float o1 = fmaxf(a01 + a11 + a21 + a31 + bv2.y, 0.f);
        const unsigned short h0 = f2bf(o0);
        const unsigned short h1 = f2bf(o1);
        const float f0 = __uint_as_float((unsigned)h0 << 16);
        const float f1 = __uint_as_float((unsigned)h1 << 16);
        const unsigned short l0 = f2bf(o0 - f0);
        const unsigned short l1 = f2bf(o1 - f1);
        unsigned* orow = (unsigned*)(xout + (size_t)(ci * N_ + t) * KP_);
        orow[(c0 >> 1) + lane]       = ((unsigned)h1 << 16) | h0;
        orow[128 + (c0 >> 1) + lane] = ((unsigned)l1 << 16) | l0;
    }
#undef EDGE
}

// ----------------------------------------------------------------- pool ----
__global__ __launch_bounds__(256) void pool_kernel(
    const __hip_bfloat16* __restrict__ xpack, int inst0, float* __restrict__ pooled)
{
    const int ci = blockIdx.x;
    const int c  = threadIdx.x;
    const __hip_bfloat16* xp = xpack + (size_t)ci * N_ * KP_;
    float a0 = 0.f, a1 = 0.f, a2 = 0.f, a3 = 0.f;
    for (int n = 0; n < N_; n += 4) {
        a0 += __bfloat162float(xp[(size_t)(n + 0) * KP_ + c]) + __bfloat162float(xp[(size_t)(n + 0) * KP_ + H_ + c]);
        a1 += __bfloat162float(xp[(size_t)(n + 1) * KP_ + c]) + __bfloat162float(xp[(size_t)(n + 1) * KP_ + H_ + c]);
        a2 += __bfloat162float(xp[(size_t)(n + 2) * KP_ + c]) + __bfloat162float(xp[(size_t)(n + 2) * KP_ + H_ + c]);
        a3 += __bfloat162float(xp[(size_t)(n + 3) * KP_ + c]) + __bfloat162float(xp[(size_t)(n + 3) * KP_ + H_ + c]);
    }
    pooled[(size_t)(inst0 + ci) * H_ + c] = (a0 + a1 + a2 + a3) * (1.0f / N_);
}

// ------------------------------------------------------------------- fc ----
__global__ __launch_bounds__(256) void fc_kernel(
    const float* __restrict__ pooled, const float* __restrict__ hf,
    const float* __restrict__ af, const float* __restrict__ fcW,
    const float* __restrict__ fcb, float* __restrict__ outp)
{
    const int idx = blockIdx.x * 256 + threadIdx.x;
    if (idx >= G_ * C_) return;
    const int gi = idx / C_;
    const int c  = idx % C_;
    float acc = fcb[c];
    const float* ph = pooled + (size_t)gi * H_;
    const float* pa = pooled + (size_t)(G_ + gi) * H_;
    for (int j = 0; j < H_; ++j) acc += ph[j] * fcW[j * C_ + c];
    for (int j = 0; j < FG; ++j) acc += hf[gi * FG + j] * fcW[(H_ + j) * C_ + c];
    for (int j = 0; j < H_; ++j) acc += pa[j] * fcW[(H_ + FG + j) * C_ + c];
    for (int j = 0; j < FG; ++j) acc += af[gi * FG + j] * fcW[(H_ + FG + H_ + j) * C_ + c];
    outp[idx] = acc;
}

// ----------------------------------------------------------------- host ----
static inline size_t align_up(size_t v, size_t a) { return (v + a - 1) & ~(a - 1); }

extern "C" void kernel_launch(void* const* d_in, const int* in_sizes, int n_in,
                              void* d_out, int out_size, void* d_ws, size_t ws_size,
                              hipStream_t stream)
{
    const float* hx  = (const float*)d_in[0];
    const float* ax  = (const float*)d_in[1];
    const int*   hei = (const int*)d_in[2];
    const int*   aei = (const int*)d_in[3];
    const float* hew = (const float*)d_in[4];
    const float* aew = (const float*)d_in[5];
    const float* hf  = (const float*)d_in[6];
    const float* af  = (const float*)d_in[7];
    const float* W0  = (const float*)d_in[8];
    const float* Wh  = (const float*)d_in[9];
    const float* bs  = (const float*)d_in[10];
    const float* fcW = (const float*)d_in[11];
    const float* fcb = (const float*)d_in[12];
    float* outp = (float*)d_out;

    const size_t pooled_b = align_up((size_t)B_ * H_ * sizeof(float), 256);
    const size_t wtp_b    = align_up((size_t)(L_ - 1) * H_ * KP_ * sizeof(__hip_bfloat16), 256);
    const size_t ep_b   = align_up((size_t)ET_ * sizeof(unsigned), 256);
    const size_t rp_b   = align_up((size_t)(N_ + 1) * sizeof(int), 256);
    const size_t xa_b   = align_up((size_t)N_ * KPH * sizeof(unsigned short), 256);
    const size_t xb_b   = align_up((size_t)N_ * KP_ * sizeof(unsigned short), 256);
    const size_t per_inst = ep_b + rp_b + xa_b + xb_b;
    const size_t fixed = pooled_b + wtp_b;

    int CB = (int)((ws_size > fixed) ? (ws_size - fixed) / per_inst : 0);
    if (CB < 1) CB = 1;
    if (CB > B_) CB = B_;

    char* p = (char*)d_ws;
    float* pooled = (float*)p;                   p += pooled_b;
    __hip_bfloat16* WTpack = (__hip_bfloat16*)p; p += wtp_b;
    unsigned* epack = (unsigned*)p;              p += (size_t)CB * ep_b;
    int* rowptr = (int*)p;                       p += (size_t)CB * rp_b;
    unsigned short* xpA = (unsigned short*)p;    p += (size_t)CB * xa_b;
    unsigned short* xpB = (unsigned short*)p;

    wsplit_kernel<<<((L_ - 1) * H_ * H_ + 255) / 256, 256, 0, stream>>>(Wh, WTpack);

    for (int i0 = 0; i0 < B_; i0 += CB) {
        const int cb = (B_ - i0 < CB) ? (B_ - i0) : CB;

        prep_kernel<<<cb, 256, 0, stream>>>(hei, aei, hew, aew, i0, epack, rowptr);
        xw0_kernel<<<cb * 32, 256, 0, stream>>>(hx, ax, W0, i0, xpA);

        for (int l = 0; l < L_; ++l) {
            if (l > 0) {
                gemm_mfma_kernel<<<cb * 8, 256, 0, stream>>>(
                    (const short*)xpB,
                    (const short*)(WTpack + (size_t)(l - 1) * H_ * KP_),
                    xpA);
            }
            agg_kernel<<<cb * 4, 1024, 0, stream>>>(
                xpA, epack, rowptr, bs + (size_t)l * H_, xpB);
        }
        pool_kernel<<<cb, 256, 0, stream>>>((const __hip_bfloat16*)xpB, i0, pooled);
    }

    fc_kernel<<<(G_ * C_ + 255) / 256, 256, 0, stream>>>(pooled, hf, af, fcW, fcb, outp);
}